// Round 7
// baseline (541.320 us; speedup 1.0000x reference)
//
#include <hip/hip_runtime.h>
#include <math.h>

#define NN 65536
#define NE 1048576
#define DEG_SCALE 33554432.0f  // 2^25

__device__ inline float4 f4fma(float s, float4 v, float4 a) {
    a.x = fmaf(s, v.x, a.x);
    a.y = fmaf(s, v.y, a.y);
    a.z = fmaf(s, v.z, a.z);
    a.w = fmaf(s, v.w, a.w);
    return a;
}

// ---------------- setup kernels ----------------

// one 64-bit atomic per edge: high32 = count, low32 = fixed-point(ew * 2^25).
// atomic returns old value -> old count == this edge's rank within its target bin.
__global__ void __launch_bounds__(256) deg_count(const int* __restrict__ col,
                                                 const float* __restrict__ ew,
                                                 unsigned long long* __restrict__ cntdeg,
                                                 int* __restrict__ rank) {
    int e = blockIdx.x * 256 + threadIdx.x;
    if (e < NE) {
        int c = col[e];
        unsigned long long p = (1ull << 32) | (unsigned long long)__float2uint_rn(ew[e] * DEG_SCALE);
        unsigned long long old = atomicAdd(&cntdeg[c], p);
        rank[e] = (int)(old >> 32);
    }
}

// phase 1: per-block (256 nodes) exclusive scan of counts; emit block total + dinv.
__global__ void __launch_bounds__(256) scan1(const unsigned long long* __restrict__ cntdeg,
                                             int* __restrict__ row_ptr,
                                             int* __restrict__ blocksum,
                                             float* __restrict__ dinv) {
    __shared__ int ls[256];
    const int t = threadIdx.x;
    const int i = blockIdx.x * 256 + t;
    unsigned long long v = cntdeg[i];
    const int c = (int)(v >> 32);
    float deg = (float)(unsigned)(v & 0xffffffffull) * (1.0f / DEG_SCALE) + 1.0f;
    dinv[i] = 1.0f / sqrtf(deg);
    ls[t] = c;
    __syncthreads();
#pragma unroll
    for (int off = 1; off < 256; off <<= 1) {
        int u = (t >= off) ? ls[t - off] : 0;
        __syncthreads();
        ls[t] += u;
        __syncthreads();
    }
    row_ptr[i] = ls[t] - c;  // exclusive
    if (t == 255) blocksum[blockIdx.x] = ls[255];
}

// phase 2: single block scans the 256 block sums -> exclusive bases; writes total.
__global__ void __launch_bounds__(256) scan2(int* __restrict__ blocksum,
                                             int* __restrict__ blockbase,
                                             int* __restrict__ row_ptr) {
    __shared__ int ls[256];
    const int t = threadIdx.x;
    const int c = blocksum[t];
    ls[t] = c;
    __syncthreads();
#pragma unroll
    for (int off = 1; off < 256; off <<= 1) {
        int u = (t >= off) ? ls[t - off] : 0;
        __syncthreads();
        ls[t] += u;
        __syncthreads();
    }
    blockbase[t] = ls[t] - c;
    if (t == 255) row_ptr[NN] = ls[255];
}

// phase 3: broadcast-add block base.
__global__ void __launch_bounds__(256) scan3(int* __restrict__ row_ptr,
                                             const int* __restrict__ blockbase) {
    const int i = blockIdx.x * 256 + threadIdx.x;
    row_ptr[i] += blockbase[blockIdx.x];
}

// atomic-free CSR fill using precomputed rank.
__global__ void __launch_bounds__(256) fill_kernel(const int* __restrict__ row,
                                                   const int* __restrict__ col,
                                                   const float* __restrict__ ew,
                                                   const float* __restrict__ dinv,
                                                   const int* __restrict__ row_ptr,
                                                   const int* __restrict__ rank,
                                                   int2* __restrict__ epack) {
    int e = blockIdx.x * 256 + threadIdx.x;
    if (e < NE) {
        int c = col[e], r = row[e];
        int idx = row_ptr[c] + rank[e];
        int2 p;
        p.x = r;
        p.y = __float_as_int(dinv[r] * ew[e] * dinv[c]);
        epack[idx] = p;
    }
}

// ---------------- per-layer kernels ----------------

// C[NN x 64] = A[NN x K] @ W[K x 64]; 64-node x 64-col tile per block, 4x4 per thread.
template <int K>
__global__ void __launch_bounds__(256) mm64t(const float* __restrict__ A,
                                             const float* __restrict__ W,
                                             float* __restrict__ C) {
    __shared__ float As[64 * 68];
    __shared__ float Ws[64 * 64];
    const int tid = threadIdx.x;
    const int tx = tid & 15;
    const int ty = tid >> 4;
    const int node0 = blockIdx.x * 64;
    float4 acc[4];
#pragma unroll
    for (int m = 0; m < 4; ++m) acc[m] = make_float4(0.f, 0.f, 0.f, 0.f);

    for (int kc = 0; kc < K; kc += 64) {
#pragma unroll
        for (int p = 0; p < 4; ++p) {
            int idx = tid + p * 256;
            int r = idx >> 4, c4 = idx & 15;
            float4 v = *reinterpret_cast<const float4*>(A + (size_t)(node0 + r) * K + kc + c4 * 4);
            *reinterpret_cast<float4*>(&As[r * 68 + c4 * 4]) = v;
        }
#pragma unroll
        for (int p = 0; p < 4; ++p) {
            int idx = tid + p * 256;
            int r = idx >> 4, c4 = idx & 15;
            float4 v = *reinterpret_cast<const float4*>(W + (size_t)(kc + r) * 64 + c4 * 4);
            *reinterpret_cast<float4*>(&Ws[r * 64 + c4 * 4]) = v;
        }
        __syncthreads();
#pragma unroll 16
        for (int k = 0; k < 64; ++k) {
            float4 w = *reinterpret_cast<const float4*>(&Ws[k * 64 + tx * 4]);
            float a0 = As[(ty * 4 + 0) * 68 + k];
            float a1 = As[(ty * 4 + 1) * 68 + k];
            float a2 = As[(ty * 4 + 2) * 68 + k];
            float a3 = As[(ty * 4 + 3) * 68 + k];
            acc[0] = f4fma(a0, w, acc[0]);
            acc[1] = f4fma(a1, w, acc[1]);
            acc[2] = f4fma(a2, w, acc[2]);
            acc[3] = f4fma(a3, w, acc[3]);
        }
        __syncthreads();
    }
#pragma unroll
    for (int m = 0; m < 4; ++m)
        *reinterpret_cast<float4*>(C + (size_t)(node0 + ty * 4 + m) * 64 + tx * 4) = acc[m];
}

// out[n][:] = act( b + dinv[n]^2*T[n] + sum_e enorm[e]*T[esrc[e]] )
// wave per node; 4 edge-groups x 16 lanes (float4/lane), 4x unrolled.
template <bool RELU>
__global__ void __launch_bounds__(256) gather64(const float* __restrict__ T,
                                                const float* __restrict__ bias,
                                                const float* __restrict__ dinv,
                                                const int* __restrict__ row_ptr,
                                                const int2* __restrict__ epack,
                                                float* __restrict__ out) {
    const int tid = threadIdx.x;
    const int lane = tid & 63;
    const int g = lane >> 4;   // edge group 0..3
    const int l = lane & 15;   // float4 index within row
    const int node = blockIdx.x * 4 + (tid >> 6);
    const float4* T4 = reinterpret_cast<const float4*>(T);

    const float dv = dinv[node];
    float4 acc = make_float4(0.f, 0.f, 0.f, 0.f);
    if (g == 0) {
        float4 b4 = reinterpret_cast<const float4*>(bias)[l];
        float4 ts = T4[(size_t)node * 16 + l];
        acc.x = b4.x + dv * dv * ts.x;
        acc.y = b4.y + dv * dv * ts.y;
        acc.z = b4.z + dv * dv * ts.z;
        acc.w = b4.w + dv * dv * ts.w;
    }
    const int s = row_ptr[node];
    const int e = row_ptr[node + 1];
    int i = s + g;
    for (; i + 12 < e; i += 16) {
        int2 p0 = epack[i];
        int2 p1 = epack[i + 4];
        int2 p2 = epack[i + 8];
        int2 p3 = epack[i + 12];
        float4 r0 = T4[(size_t)p0.x * 16 + l];
        float4 r1 = T4[(size_t)p1.x * 16 + l];
        float4 r2 = T4[(size_t)p2.x * 16 + l];
        float4 r3 = T4[(size_t)p3.x * 16 + l];
        acc = f4fma(__int_as_float(p0.y), r0, acc);
        acc = f4fma(__int_as_float(p1.y), r1, acc);
        acc = f4fma(__int_as_float(p2.y), r2, acc);
        acc = f4fma(__int_as_float(p3.y), r3, acc);
    }
    for (; i < e; i += 4) {
        int2 p0 = epack[i];
        acc = f4fma(__int_as_float(p0.y), T4[(size_t)p0.x * 16 + l], acc);
    }
    acc.x += __shfl_xor(acc.x, 16);
    acc.y += __shfl_xor(acc.y, 16);
    acc.z += __shfl_xor(acc.z, 16);
    acc.w += __shfl_xor(acc.w, 16);
    acc.x += __shfl_xor(acc.x, 32);
    acc.y += __shfl_xor(acc.y, 32);
    acc.z += __shfl_xor(acc.z, 32);
    acc.w += __shfl_xor(acc.w, 32);
    if (RELU) {
        acc.x = fmaxf(acc.x, 0.f);
        acc.y = fmaxf(acc.y, 0.f);
        acc.z = fmaxf(acc.z, 0.f);
        acc.w = fmaxf(acc.w, 0.f);
    }
    if (g == 0) reinterpret_cast<float4*>(out)[(size_t)node * 16 + l] = acc;
}

// Fused layer (uses agg(X@W) == agg(X)@W):
// Anext = relu( agg(Aprev) @ W + b ). Block = 64 nodes: gather agg into LDS, then LDS GEMM.
__global__ void __launch_bounds__(256) gmm(const float* __restrict__ Aprev,
                                           const float* __restrict__ W,
                                           const float* __restrict__ bias,
                                           const float* __restrict__ dinv,
                                           const int* __restrict__ row_ptr,
                                           const int2* __restrict__ epack,
                                           float* __restrict__ Anext) {
    __shared__ float Ag[64 * 68];
    __shared__ float Ws[64 * 64];
    const int tid = threadIdx.x;
    const int node0 = blockIdx.x * 64;
    const float4* T4 = reinterpret_cast<const float4*>(Aprev);

    // stage W
#pragma unroll
    for (int p = 0; p < 4; ++p) {
        int idx = tid + p * 256;
        int r = idx >> 4, c4 = idx & 15;
        *reinterpret_cast<float4*>(&Ws[r * 64 + c4 * 4]) =
            *reinterpret_cast<const float4*>(W + (size_t)r * 64 + c4 * 4);
    }

    // phase 1: gather agg for 64 nodes (each wave: 16 nodes serially)
    const int w = tid >> 6;
    const int lane = tid & 63;
    const int g = lane >> 4;
    const int l = lane & 15;
    for (int j = 0; j < 16; ++j) {
        const int nrow = w * 16 + j;
        const int node = node0 + nrow;
        float4 acc = make_float4(0.f, 0.f, 0.f, 0.f);
        if (g == 0) {
            const float dv = dinv[node];
            float4 ts = T4[(size_t)node * 16 + l];
            acc.x = dv * dv * ts.x;
            acc.y = dv * dv * ts.y;
            acc.z = dv * dv * ts.z;
            acc.w = dv * dv * ts.w;
        }
        const int s = row_ptr[node];
        const int e = row_ptr[node + 1];
        int i = s + g;
        for (; i + 12 < e; i += 16) {
            int2 p0 = epack[i];
            int2 p1 = epack[i + 4];
            int2 p2 = epack[i + 8];
            int2 p3 = epack[i + 12];
            float4 r0 = T4[(size_t)p0.x * 16 + l];
            float4 r1 = T4[(size_t)p1.x * 16 + l];
            float4 r2 = T4[(size_t)p2.x * 16 + l];
            float4 r3 = T4[(size_t)p3.x * 16 + l];
            acc = f4fma(__int_as_float(p0.y), r0, acc);
            acc = f4fma(__int_as_float(p1.y), r1, acc);
            acc = f4fma(__int_as_float(p2.y), r2, acc);
            acc = f4fma(__int_as_float(p3.y), r3, acc);
        }
        for (; i < e; i += 4) {
            int2 p0 = epack[i];
            acc = f4fma(__int_as_float(p0.y), T4[(size_t)p0.x * 16 + l], acc);
        }
        acc.x += __shfl_xor(acc.x, 16);
        acc.y += __shfl_xor(acc.y, 16);
        acc.z += __shfl_xor(acc.z, 16);
        acc.w += __shfl_xor(acc.w, 16);
        acc.x += __shfl_xor(acc.x, 32);
        acc.y += __shfl_xor(acc.y, 32);
        acc.z += __shfl_xor(acc.z, 32);
        acc.w += __shfl_xor(acc.w, 32);
        if (g == 0) *reinterpret_cast<float4*>(&Ag[nrow * 68 + l * 4]) = acc;
    }
    __syncthreads();

    // phase 2: Anext = relu(Ag @ Ws + b)
    const int tx = tid & 15;
    const int ty = tid >> 4;
    float4 acc[4];
#pragma unroll
    for (int m = 0; m < 4; ++m) acc[m] = make_float4(0.f, 0.f, 0.f, 0.f);
#pragma unroll 16
    for (int k = 0; k < 64; ++k) {
        float4 w4 = *reinterpret_cast<const float4*>(&Ws[k * 64 + tx * 4]);
        float a0 = Ag[(ty * 4 + 0) * 68 + k];
        float a1 = Ag[(ty * 4 + 1) * 68 + k];
        float a2 = Ag[(ty * 4 + 2) * 68 + k];
        float a3 = Ag[(ty * 4 + 3) * 68 + k];
        acc[0] = f4fma(a0, w4, acc[0]);
        acc[1] = f4fma(a1, w4, acc[1]);
        acc[2] = f4fma(a2, w4, acc[2]);
        acc[3] = f4fma(a3, w4, acc[3]);
    }
    float4 b4 = *reinterpret_cast<const float4*>(bias + tx * 4);
#pragma unroll
    for (int m = 0; m < 4; ++m) {
        float4 r;
        r.x = fmaxf(acc[m].x + b4.x, 0.f);
        r.y = fmaxf(acc[m].y + b4.y, 0.f);
        r.z = fmaxf(acc[m].z + b4.z, 0.f);
        r.w = fmaxf(acc[m].w + b4.w, 0.f);
        *reinterpret_cast<float4*>(Anext + (size_t)(node0 + ty * 4 + m) * 64 + tx * 4) = r;
    }
}

// T8[NN x 2] = A[NN x 64] @ W8[64 x 2]; wave per node, shuffle reduction.
__global__ void __launch_bounds__(256) mm2(const float* __restrict__ A,
                                           const float* __restrict__ W8,
                                           float* __restrict__ T8) {
    const int lane = threadIdx.x & 63;
    const int node = blockIdx.x * 4 + (threadIdx.x >> 6);
    const float a = A[(size_t)node * 64 + lane];
    float p0 = a * W8[lane * 2 + 0];
    float p1 = a * W8[lane * 2 + 1];
    for (int o = 32; o > 0; o >>= 1) {
        p0 += __shfl_xor(p0, o);
        p1 += __shfl_xor(p1, o);
    }
    if (lane == 0) {
        T8[node * 2 + 0] = p0;
        T8[node * 2 + 1] = p1;
    }
}

// wave per node; lane = (edge j 0..31) x (col c 0..1).
__global__ void __launch_bounds__(256) gather2(const float* __restrict__ T8,
                                               const float* __restrict__ b8,
                                               const float* __restrict__ dinv,
                                               const int* __restrict__ row_ptr,
                                               const int2* __restrict__ epack,
                                               float* __restrict__ out) {
    const int lane = threadIdx.x & 63;
    const int c = lane & 1;
    const int j = lane >> 1;  // 0..31
    const int node = blockIdx.x * 4 + (threadIdx.x >> 6);
    const int s = row_ptr[node];
    const int e = row_ptr[node + 1];
    float acc = 0.f;
    for (int i = s + j; i < e; i += 32) {
        int2 p = epack[i];
        acc += __int_as_float(p.y) * T8[(size_t)p.x * 2 + c];
    }
    acc += __shfl_xor(acc, 2);
    acc += __shfl_xor(acc, 4);
    acc += __shfl_xor(acc, 8);
    acc += __shfl_xor(acc, 16);
    acc += __shfl_xor(acc, 32);
    if (j == 0) {
        const float dv = dinv[node];
        out[(size_t)node * 2 + c] = b8[c] + dv * dv * T8[(size_t)node * 2 + c] + acc;
    }
}

// ---------------- launcher ----------------

extern "C" void kernel_launch(void* const* d_in, const int* in_sizes, int n_in,
                              void* d_out, int out_size, void* d_ws, size_t ws_size,
                              hipStream_t stream) {
    const float* x  = (const float*)d_in[0];
    const int*   ei = (const int*)d_in[1];   // [2, NE]: [0:NE)=row(src), [NE:2NE)=col(dst)
    const float* ea = (const float*)d_in[2];
    const float* W1 = (const float*)d_in[3];
    const float* b1 = (const float*)d_in[4];
    const float* W2 = (const float*)d_in[5];
    const float* b2 = (const float*)d_in[6];
    const float* W3 = (const float*)d_in[7];
    const float* b3 = (const float*)d_in[8];
    const float* W4 = (const float*)d_in[9];
    const float* b4 = (const float*)d_in[10];
    const float* W5 = (const float*)d_in[11];
    const float* b5 = (const float*)d_in[12];
    const float* W8 = (const float*)d_in[13];
    const float* b8 = (const float*)d_in[14];
    float* out = (float*)d_out;

    // workspace layout (fp32/i32 words)
    float* T      = (float*)d_ws;                 // NN*64
    float* A      = T + (size_t)NN * 64;          // NN*64  (rank aliases A: rank is dead
    int*   rank   = (int*)A;                      //         before gather64 first writes A)
    int2*  epack  = (int2*)(A + (size_t)NN * 64); // NE int2
    unsigned long long* cntdeg = (unsigned long long*)(epack + NE);  // NN ull
    float* dinv   = (float*)(cntdeg + NN);        // NN
    int*   row_ptr= (int*)(dinv + NN);            // NN+1
    float* T8     = (float*)(row_ptr + NN + 1);   // NN*2
    int*   blocksum  = (int*)(T8 + (size_t)NN * 2);  // 256
    int*   blockbase = blocksum + 256;               // 256

    const int* e_row = ei;
    const int* e_col = ei + NE;

    (void)hipMemsetAsync(cntdeg, 0, (size_t)NN * 8, stream);

    deg_count<<<NE / 256, 256, 0, stream>>>(e_col, ea, cntdeg, rank);
    scan1<<<NN / 256, 256, 0, stream>>>(cntdeg, row_ptr, blocksum, dinv);
    scan2<<<1, 256, 0, stream>>>(blocksum, blockbase, row_ptr);
    scan3<<<NN / 256, 256, 0, stream>>>(row_ptr, blockbase);
    fill_kernel<<<NE / 256, 256, 0, stream>>>(e_row, e_col, ea, dinv, row_ptr, rank, epack);

    // layer 1: transform first (128 -> 64), then aggregate
    mm64t<128><<<NN / 64, 256, 0, stream>>>(x, W1, T);
    gather64<true><<<NN / 4, 256, 0, stream>>>(T, b1, dinv, row_ptr, epack, A);
    // layers 2..5: fused aggregate-then-transform (agg(X)@W == agg(X@W))
    gmm<<<NN / 64, 256, 0, stream>>>(A, W2, b2, dinv, row_ptr, epack, T);
    gmm<<<NN / 64, 256, 0, stream>>>(T, W3, b3, dinv, row_ptr, epack, A);
    gmm<<<NN / 64, 256, 0, stream>>>(A, W4, b4, dinv, row_ptr, epack, T);
    gmm<<<NN / 64, 256, 0, stream>>>(T, W5, b5, dinv, row_ptr, epack, A);
    // layer 8: transform first (64 -> 2), then aggregate in 2-dim space
    mm2<<<NN / 4, 256, 0, stream>>>(A, W8, T8);
    gather2<<<NN / 4, 256, 0, stream>>>(T8, b8, dinv, row_ptr, epack, out);
}

// Round 8
// 377.591 us; speedup vs baseline: 1.4336x; 1.4336x over previous
//
#include <hip/hip_runtime.h>
#include <math.h>

#define NN 65536
#define NE 1048576
#define DEG_SCALE 33554432.0f  // 2^25

__device__ inline float4 f4fma(float s, float4 v, float4 a) {
    a.x = fmaf(s, v.x, a.x);
    a.y = fmaf(s, v.y, a.y);
    a.z = fmaf(s, v.z, a.z);
    a.w = fmaf(s, v.w, a.w);
    return a;
}

// ---------------- setup kernels ----------------

// one 64-bit atomic per edge: high32 = count, low32 = fixed-point(ew * 2^25).
// atomic returns old value -> old count == this edge's rank within its target bin.
__global__ void __launch_bounds__(256) deg_count(const int* __restrict__ col,
                                                 const float* __restrict__ ew,
                                                 unsigned long long* __restrict__ cntdeg,
                                                 int* __restrict__ rank) {
    int e = blockIdx.x * 256 + threadIdx.x;
    if (e < NE) {
        int c = col[e];
        unsigned long long p = (1ull << 32) | (unsigned long long)__float2uint_rn(ew[e] * DEG_SCALE);
        unsigned long long old = atomicAdd(&cntdeg[c], p);
        rank[e] = (int)(old >> 32);
    }
}

// phase 1: per-block (256 nodes) exclusive scan of counts; emit block total + dinv.
__global__ void __launch_bounds__(256) scan1(const unsigned long long* __restrict__ cntdeg,
                                             int* __restrict__ row_ptr,
                                             int* __restrict__ blocksum,
                                             float* __restrict__ dinv) {
    __shared__ int ls[256];
    const int t = threadIdx.x;
    const int i = blockIdx.x * 256 + t;
    unsigned long long v = cntdeg[i];
    const int c = (int)(v >> 32);
    float deg = (float)(unsigned)(v & 0xffffffffull) * (1.0f / DEG_SCALE) + 1.0f;
    dinv[i] = 1.0f / sqrtf(deg);
    ls[t] = c;
    __syncthreads();
#pragma unroll
    for (int off = 1; off < 256; off <<= 1) {
        int u = (t >= off) ? ls[t - off] : 0;
        __syncthreads();
        ls[t] += u;
        __syncthreads();
    }
    row_ptr[i] = ls[t] - c;  // exclusive
    if (t == 255) blocksum[blockIdx.x] = ls[255];
}

// phase 2: single block scans the 256 block sums -> exclusive bases; writes total.
__global__ void __launch_bounds__(256) scan2(int* __restrict__ blocksum,
                                             int* __restrict__ blockbase,
                                             int* __restrict__ row_ptr) {
    __shared__ int ls[256];
    const int t = threadIdx.x;
    const int c = blocksum[t];
    ls[t] = c;
    __syncthreads();
#pragma unroll
    for (int off = 1; off < 256; off <<= 1) {
        int u = (t >= off) ? ls[t - off] : 0;
        __syncthreads();
        ls[t] += u;
        __syncthreads();
    }
    blockbase[t] = ls[t] - c;
    if (t == 255) row_ptr[NN] = ls[255];
}

// phase 3: broadcast-add block base.
__global__ void __launch_bounds__(256) scan3(int* __restrict__ row_ptr,
                                             const int* __restrict__ blockbase) {
    const int i = blockIdx.x * 256 + threadIdx.x;
    row_ptr[i] += blockbase[blockIdx.x];
}

// atomic-free CSR fill using precomputed rank.
__global__ void __launch_bounds__(256) fill_kernel(const int* __restrict__ row,
                                                   const int* __restrict__ col,
                                                   const float* __restrict__ ew,
                                                   const float* __restrict__ dinv,
                                                   const int* __restrict__ row_ptr,
                                                   const int* __restrict__ rank,
                                                   int2* __restrict__ epack) {
    int e = blockIdx.x * 256 + threadIdx.x;
    if (e < NE) {
        int c = col[e], r = row[e];
        int idx = row_ptr[c] + rank[e];
        int2 p;
        p.x = r;
        p.y = __float_as_int(dinv[r] * ew[e] * dinv[c]);
        epack[idx] = p;
    }
}

// ---------------- per-layer kernels ----------------

// C[NN x 64] = A[NN x K] @ W[K x 64]; 64-node x 64-col tile per block, 4x4 per thread.
template <int K>
__global__ void __launch_bounds__(256) mm64t(const float* __restrict__ A,
                                             const float* __restrict__ W,
                                             float* __restrict__ C) {
    __shared__ float As[64 * 68];
    __shared__ float Ws[64 * 64];
    const int tid = threadIdx.x;
    const int tx = tid & 15;
    const int ty = tid >> 4;
    const int node0 = blockIdx.x * 64;
    float4 acc[4];
#pragma unroll
    for (int m = 0; m < 4; ++m) acc[m] = make_float4(0.f, 0.f, 0.f, 0.f);

    for (int kc = 0; kc < K; kc += 64) {
#pragma unroll
        for (int p = 0; p < 4; ++p) {
            int idx = tid + p * 256;
            int r = idx >> 4, c4 = idx & 15;
            float4 v = *reinterpret_cast<const float4*>(A + (size_t)(node0 + r) * K + kc + c4 * 4);
            *reinterpret_cast<float4*>(&As[r * 68 + c4 * 4]) = v;
        }
#pragma unroll
        for (int p = 0; p < 4; ++p) {
            int idx = tid + p * 256;
            int r = idx >> 4, c4 = idx & 15;
            float4 v = *reinterpret_cast<const float4*>(W + (size_t)(kc + r) * 64 + c4 * 4);
            *reinterpret_cast<float4*>(&Ws[r * 64 + c4 * 4]) = v;
        }
        __syncthreads();
#pragma unroll 16
        for (int k = 0; k < 64; ++k) {
            float4 w = *reinterpret_cast<const float4*>(&Ws[k * 64 + tx * 4]);
            float a0 = As[(ty * 4 + 0) * 68 + k];
            float a1 = As[(ty * 4 + 1) * 68 + k];
            float a2 = As[(ty * 4 + 2) * 68 + k];
            float a3 = As[(ty * 4 + 3) * 68 + k];
            acc[0] = f4fma(a0, w, acc[0]);
            acc[1] = f4fma(a1, w, acc[1]);
            acc[2] = f4fma(a2, w, acc[2]);
            acc[3] = f4fma(a3, w, acc[3]);
        }
        __syncthreads();
    }
#pragma unroll
    for (int m = 0; m < 4; ++m)
        *reinterpret_cast<float4*>(C + (size_t)(node0 + ty * 4 + m) * 64 + tx * 4) = acc[m];
}

// out[n][:] = act( b + dinv[n]^2*T[n] + sum_e enorm[e]*T[esrc[e]] )
// 16-lane group per node (16 nodes/block); 8-wide clamped-predicated edge loop:
// always issue 8 epack + 8 row loads, invalid slots clamped to a valid index, scale 0.
template <bool RELU>
__global__ void __launch_bounds__(256) gather64(const float* __restrict__ T,
                                                const float* __restrict__ bias,
                                                const float* __restrict__ dinv,
                                                const int* __restrict__ row_ptr,
                                                const int2* __restrict__ epack,
                                                float* __restrict__ out) {
    const int tid = threadIdx.x;
    const int l = tid & 15;                       // float4 index within row
    const int node = blockIdx.x * 16 + (tid >> 4);
    const float4* T4 = reinterpret_cast<const float4*>(T);

    const float dv = dinv[node];
    float4 b4 = reinterpret_cast<const float4*>(bias)[l];
    float4 ts = T4[(size_t)node * 16 + l];
    float4 acc;
    acc.x = b4.x + dv * dv * ts.x;
    acc.y = b4.y + dv * dv * ts.y;
    acc.z = b4.z + dv * dv * ts.z;
    acc.w = b4.w + dv * dv * ts.w;

    const int s = row_ptr[node];
    const int e = row_ptr[node + 1];
    for (int i0 = s; i0 < e; i0 += 8) {
        int2 p[8];
#pragma unroll
        for (int j = 0; j < 8; ++j) {
            int ii = i0 + j;
            p[j] = epack[ii < e ? ii : i0];       // slot 0 always valid
        }
        float4 r[8];
        float n[8];
#pragma unroll
        for (int j = 0; j < 8; ++j) {
            n[j] = (i0 + j < e) ? __int_as_float(p[j].y) : 0.0f;
            r[j] = T4[(size_t)p[j].x * 16 + l];
        }
#pragma unroll
        for (int j = 0; j < 8; ++j) acc = f4fma(n[j], r[j], acc);
    }
    if (RELU) {
        acc.x = fmaxf(acc.x, 0.f);
        acc.y = fmaxf(acc.y, 0.f);
        acc.z = fmaxf(acc.z, 0.f);
        acc.w = fmaxf(acc.w, 0.f);
    }
    reinterpret_cast<float4*>(out)[(size_t)node * 16 + l] = acc;
}

// T8[NN x 2] = A[NN x 64] @ W8[64 x 2]; wave per node, shuffle reduction.
__global__ void __launch_bounds__(256) mm2(const float* __restrict__ A,
                                           const float* __restrict__ W8,
                                           float* __restrict__ T8) {
    const int lane = threadIdx.x & 63;
    const int node = blockIdx.x * 4 + (threadIdx.x >> 6);
    const float a = A[(size_t)node * 64 + lane];
    float p0 = a * W8[lane * 2 + 0];
    float p1 = a * W8[lane * 2 + 1];
    for (int o = 32; o > 0; o >>= 1) {
        p0 += __shfl_xor(p0, o);
        p1 += __shfl_xor(p1, o);
    }
    if (lane == 0) {
        T8[node * 2 + 0] = p0;
        T8[node * 2 + 1] = p1;
    }
}

// wave per node; lane = (edge j 0..31) x (col c 0..1).
__global__ void __launch_bounds__(256) gather2(const float* __restrict__ T8,
                                               const float* __restrict__ b8,
                                               const float* __restrict__ dinv,
                                               const int* __restrict__ row_ptr,
                                               const int2* __restrict__ epack,
                                               float* __restrict__ out) {
    const int lane = threadIdx.x & 63;
    const int c = lane & 1;
    const int j = lane >> 1;  // 0..31
    const int node = blockIdx.x * 4 + (threadIdx.x >> 6);
    const int s = row_ptr[node];
    const int e = row_ptr[node + 1];
    float acc = 0.f;
    for (int i = s + j; i < e; i += 32) {
        int2 p = epack[i];
        acc += __int_as_float(p.y) * T8[(size_t)p.x * 2 + c];
    }
    acc += __shfl_xor(acc, 2);
    acc += __shfl_xor(acc, 4);
    acc += __shfl_xor(acc, 8);
    acc += __shfl_xor(acc, 16);
    acc += __shfl_xor(acc, 32);
    if (j == 0) {
        const float dv = dinv[node];
        out[(size_t)node * 2 + c] = b8[c] + dv * dv * T8[(size_t)node * 2 + c] + acc;
    }
}

// ---------------- launcher ----------------

extern "C" void kernel_launch(void* const* d_in, const int* in_sizes, int n_in,
                              void* d_out, int out_size, void* d_ws, size_t ws_size,
                              hipStream_t stream) {
    const float* x  = (const float*)d_in[0];
    const int*   ei = (const int*)d_in[1];   // [2, NE]: [0:NE)=row(src), [NE:2NE)=col(dst)
    const float* ea = (const float*)d_in[2];
    const float* W1 = (const float*)d_in[3];
    const float* b1 = (const float*)d_in[4];
    const float* W2 = (const float*)d_in[5];
    const float* b2 = (const float*)d_in[6];
    const float* W3 = (const float*)d_in[7];
    const float* b3 = (const float*)d_in[8];
    const float* W4 = (const float*)d_in[9];
    const float* b4 = (const float*)d_in[10];
    const float* W5 = (const float*)d_in[11];
    const float* b5 = (const float*)d_in[12];
    const float* W8 = (const float*)d_in[13];
    const float* b8 = (const float*)d_in[14];
    float* out = (float*)d_out;

    // workspace layout (fp32/i32 words)
    float* T      = (float*)d_ws;                 // NN*64
    float* A      = T + (size_t)NN * 64;          // NN*64  (rank aliases A: rank is dead
    int*   rank   = (int*)A;                      //         before gather64 first writes A)
    int2*  epack  = (int2*)(A + (size_t)NN * 64); // NE int2
    unsigned long long* cntdeg = (unsigned long long*)(epack + NE);  // NN ull
    float* dinv   = (float*)(cntdeg + NN);        // NN
    int*   row_ptr= (int*)(dinv + NN);            // NN+1
    float* T8     = (float*)(row_ptr + NN + 1);   // NN*2
    int*   blocksum  = (int*)(T8 + (size_t)NN * 2);  // 256
    int*   blockbase = blocksum + 256;               // 256

    const int* e_row = ei;
    const int* e_col = ei + NE;

    (void)hipMemsetAsync(cntdeg, 0, (size_t)NN * 8, stream);

    deg_count<<<NE / 256, 256, 0, stream>>>(e_col, ea, cntdeg, rank);
    scan1<<<NN / 256, 256, 0, stream>>>(cntdeg, row_ptr, blocksum, dinv);
    scan2<<<1, 256, 0, stream>>>(blocksum, blockbase, row_ptr);
    scan3<<<NN / 256, 256, 0, stream>>>(row_ptr, blockbase);
    fill_kernel<<<NE / 256, 256, 0, stream>>>(e_row, e_col, ea, dinv, row_ptr, rank, epack);

    // layer 1: transform first (128 -> 64), then aggregate
    mm64t<128><<<NN / 64, 256, 0, stream>>>(x, W1, T);
    gather64<true><<<NN / 16, 256, 0, stream>>>(T, b1, dinv, row_ptr, epack, A);
    // layers 2..5
    mm64t<64><<<NN / 64, 256, 0, stream>>>(A, W2, T);
    gather64<true><<<NN / 16, 256, 0, stream>>>(T, b2, dinv, row_ptr, epack, A);
    mm64t<64><<<NN / 64, 256, 0, stream>>>(A, W3, T);
    gather64<true><<<NN / 16, 256, 0, stream>>>(T, b3, dinv, row_ptr, epack, A);
    mm64t<64><<<NN / 64, 256, 0, stream>>>(A, W4, T);
    gather64<true><<<NN / 16, 256, 0, stream>>>(T, b4, dinv, row_ptr, epack, A);
    mm64t<64><<<NN / 64, 256, 0, stream>>>(A, W5, T);
    gather64<true><<<NN / 16, 256, 0, stream>>>(T, b5, dinv, row_ptr, epack, A);
    // layer 8: transform first (64 -> 2), then aggregate in 2-dim space
    mm2<<<NN / 4, 256, 0, stream>>>(A, W8, T8);
    gather2<<<NN / 4, 256, 0, stream>>>(T8, b8, dinv, row_ptr, epack, out);
}

// Round 9
// 316.212 us; speedup vs baseline: 1.7119x; 1.1941x over previous
//
#include <hip/hip_runtime.h>
#include <hip/hip_bf16.h>
#include <math.h>

#define NN 65536
#define NE 1048576
#define DEG_SCALE 33554432.0f  // 2^25

__device__ inline float4 f4fma(float s, float4 v, float4 a) {
    a.x = fmaf(s, v.x, a.x);
    a.y = fmaf(s, v.y, a.y);
    a.z = fmaf(s, v.z, a.z);
    a.w = fmaf(s, v.w, a.w);
    return a;
}

__device__ inline unsigned pack2bf(float a, float b) {
    __hip_bfloat16 ha = __float2bfloat16(a), hb = __float2bfloat16(b);
    return (unsigned)*reinterpret_cast<unsigned short*>(&ha) |
           ((unsigned)*reinterpret_cast<unsigned short*>(&hb) << 16);
}

__device__ inline float4 bfx4(uint2 v) {  // 4 bf16 -> 4 fp32
    float4 r;
    r.x = __uint_as_float(v.x << 16);
    r.y = __uint_as_float(v.x & 0xffff0000u);
    r.z = __uint_as_float(v.y << 16);
    r.w = __uint_as_float(v.y & 0xffff0000u);
    return r;
}

// shared mm body: C[64 x 64](bf16) = A[64 rows x K] @ W[K x 64], 4x4 per thread.
template <int K>
__device__ void mm64_body_bf(const float* __restrict__ A, const float* __restrict__ W,
                             unsigned short* __restrict__ Cb, int node0, int tid) {
    __shared__ float As[64 * 68];
    __shared__ float Ws[64 * 64];
    const int tx = tid & 15;
    const int ty = tid >> 4;
    float4 acc[4];
#pragma unroll
    for (int m = 0; m < 4; ++m) acc[m] = make_float4(0.f, 0.f, 0.f, 0.f);

    for (int kc = 0; kc < K; kc += 64) {
#pragma unroll
        for (int p = 0; p < 4; ++p) {
            int idx = tid + p * 256;
            int r = idx >> 4, c4 = idx & 15;
            float4 v = *reinterpret_cast<const float4*>(A + (size_t)(node0 + r) * K + kc + c4 * 4);
            *reinterpret_cast<float4*>(&As[r * 68 + c4 * 4]) = v;
        }
#pragma unroll
        for (int p = 0; p < 4; ++p) {
            int idx = tid + p * 256;
            int r = idx >> 4, c4 = idx & 15;
            float4 v = *reinterpret_cast<const float4*>(W + (size_t)(kc + r) * 64 + c4 * 4);
            *reinterpret_cast<float4*>(&Ws[r * 64 + c4 * 4]) = v;
        }
        __syncthreads();
#pragma unroll 16
        for (int k = 0; k < 64; ++k) {
            float4 w = *reinterpret_cast<const float4*>(&Ws[k * 64 + tx * 4]);
            float a0 = As[(ty * 4 + 0) * 68 + k];
            float a1 = As[(ty * 4 + 1) * 68 + k];
            float a2 = As[(ty * 4 + 2) * 68 + k];
            float a3 = As[(ty * 4 + 3) * 68 + k];
            acc[0] = f4fma(a0, w, acc[0]);
            acc[1] = f4fma(a1, w, acc[1]);
            acc[2] = f4fma(a2, w, acc[2]);
            acc[3] = f4fma(a3, w, acc[3]);
        }
        __syncthreads();
    }
#pragma unroll
    for (int m = 0; m < 4; ++m) {
        uint2 pk;
        pk.x = pack2bf(acc[m].x, acc[m].y);
        pk.y = pack2bf(acc[m].z, acc[m].w);
        *reinterpret_cast<uint2*>(Cb + (size_t)(node0 + ty * 4 + m) * 64 + tx * 4) = pk;
    }
}

// ---------------- setup (merged with layer-1 mm) ----------------

// blocks with bid%5==0 run mm64t<128> (x@W1 -> Tb); others run deg_count.
// interleaved so both kinds are co-resident -> mm hides under atomic latency.
__global__ void __launch_bounds__(256) setup_mm(const int* __restrict__ col,
                                                const float* __restrict__ ew,
                                                unsigned long long* __restrict__ cntdeg,
                                                int* __restrict__ rank,
                                                const float* __restrict__ x,
                                                const float* __restrict__ W1,
                                                unsigned short* __restrict__ Tb) {
    const int bid = blockIdx.x;
    const int tid = threadIdx.x;
    if (bid % 5 == 0) {
        mm64_body_bf<128>(x, W1, Tb, (bid / 5) * 64, tid);
    } else {
        int e = (bid - bid / 5 - 1) * 256 + tid;
        if (e < NE) {
            int c = col[e];
            unsigned long long p =
                (1ull << 32) | (unsigned long long)__float2uint_rn(ew[e] * DEG_SCALE);
            unsigned long long old = atomicAdd(&cntdeg[c], p);
            rank[e] = (int)(old >> 32);
        }
    }
}

// phase 1: per-block (256 nodes) exclusive scan of counts; emit block total + dinv.
__global__ void __launch_bounds__(256) scan1(const unsigned long long* __restrict__ cntdeg,
                                             int* __restrict__ row_ptr,
                                             int* __restrict__ blocksum,
                                             float* __restrict__ dinv) {
    __shared__ int ls[256];
    const int t = threadIdx.x;
    const int i = blockIdx.x * 256 + t;
    unsigned long long v = cntdeg[i];
    const int c = (int)(v >> 32);
    float deg = (float)(unsigned)(v & 0xffffffffull) * (1.0f / DEG_SCALE) + 1.0f;
    dinv[i] = 1.0f / sqrtf(deg);
    ls[t] = c;
    __syncthreads();
#pragma unroll
    for (int off = 1; off < 256; off <<= 1) {
        int u = (t >= off) ? ls[t - off] : 0;
        __syncthreads();
        ls[t] += u;
        __syncthreads();
    }
    row_ptr[i] = ls[t] - c;  // exclusive
    if (t == 255) blocksum[blockIdx.x] = ls[255];
}

// phase 2: single block scans the 256 block sums -> exclusive bases; writes total.
__global__ void __launch_bounds__(256) scan2(int* __restrict__ blocksum,
                                             int* __restrict__ blockbase,
                                             int* __restrict__ row_ptr) {
    __shared__ int ls[256];
    const int t = threadIdx.x;
    const int c = blocksum[t];
    ls[t] = c;
    __syncthreads();
#pragma unroll
    for (int off = 1; off < 256; off <<= 1) {
        int u = (t >= off) ? ls[t - off] : 0;
        __syncthreads();
        ls[t] += u;
        __syncthreads();
    }
    blockbase[t] = ls[t] - c;
    if (t == 255) row_ptr[NN] = ls[255];
}

// phase 3: broadcast-add block base.
__global__ void __launch_bounds__(256) scan3(int* __restrict__ row_ptr,
                                             const int* __restrict__ blockbase) {
    const int i = blockIdx.x * 256 + threadIdx.x;
    row_ptr[i] += blockbase[blockIdx.x];
}

// atomic-free CSR fill using precomputed rank.
__global__ void __launch_bounds__(256) fill_kernel(const int* __restrict__ row,
                                                   const int* __restrict__ col,
                                                   const float* __restrict__ ew,
                                                   const float* __restrict__ dinv,
                                                   const int* __restrict__ row_ptr,
                                                   const int* __restrict__ rank,
                                                   int2* __restrict__ epack) {
    int e = blockIdx.x * 256 + threadIdx.x;
    if (e < NE) {
        int c = col[e], r = row[e];
        int idx = row_ptr[c] + rank[e];
        int2 p;
        p.x = r;
        p.y = __float_as_int(dinv[r] * ew[e] * dinv[c]);
        epack[idx] = p;
    }
}

// ---------------- per-layer kernels ----------------

// standalone mm for layers 2..5: A(fp32) @ W -> Tb(bf16)
__global__ void __launch_bounds__(256) mm64k(const float* __restrict__ A,
                                             const float* __restrict__ W,
                                             unsigned short* __restrict__ Tb) {
    mm64_body_bf<64>(A, W, Tb, blockIdx.x * 64, threadIdx.x);
}

// out[n][:] = act( b + dinv[n]^2*T[n] + sum_e enorm[e]*T[esrc[e]] ), T in bf16.
// 16-lane group per node (16 nodes/block); 8-wide clamped-predicated edge loop.
template <bool RELU>
__global__ void __launch_bounds__(256) gather64b(const unsigned short* __restrict__ Tb,
                                                 const float* __restrict__ bias,
                                                 const float* __restrict__ dinv,
                                                 const int* __restrict__ row_ptr,
                                                 const int2* __restrict__ epack,
                                                 float* __restrict__ out) {
    const int tid = threadIdx.x;
    const int l = tid & 15;                       // 4-col group within row
    const int node = blockIdx.x * 16 + (tid >> 4);
    const uint2* T2 = reinterpret_cast<const uint2*>(Tb);  // 4 bf16 per elem

    const float dv = dinv[node];
    float4 b4 = reinterpret_cast<const float4*>(bias)[l];
    float4 ts = bfx4(T2[(size_t)node * 16 + l]);
    float4 acc;
    acc.x = b4.x + dv * dv * ts.x;
    acc.y = b4.y + dv * dv * ts.y;
    acc.z = b4.z + dv * dv * ts.z;
    acc.w = b4.w + dv * dv * ts.w;

    const int s = row_ptr[node];
    const int e = row_ptr[node + 1];
    for (int i0 = s; i0 < e; i0 += 8) {
        int2 p[8];
#pragma unroll
        for (int j = 0; j < 8; ++j) {
            int ii = i0 + j;
            p[j] = epack[ii < e ? ii : i0];       // slot 0 always valid
        }
        uint2 r[8];
        float n[8];
#pragma unroll
        for (int j = 0; j < 8; ++j) {
            n[j] = (i0 + j < e) ? __int_as_float(p[j].y) : 0.0f;
            r[j] = T2[(size_t)p[j].x * 16 + l];
        }
#pragma unroll
        for (int j = 0; j < 8; ++j) acc = f4fma(n[j], bfx4(r[j]), acc);
    }
    if (RELU) {
        acc.x = fmaxf(acc.x, 0.f);
        acc.y = fmaxf(acc.y, 0.f);
        acc.z = fmaxf(acc.z, 0.f);
        acc.w = fmaxf(acc.w, 0.f);
    }
    reinterpret_cast<float4*>(out)[(size_t)node * 16 + l] = acc;
}

// T8[NN x 2] = A[NN x 64] @ W8[64 x 2]; wave per node, shuffle reduction. fp32.
__global__ void __launch_bounds__(256) mm2(const float* __restrict__ A,
                                           const float* __restrict__ W8,
                                           float* __restrict__ T8) {
    const int lane = threadIdx.x & 63;
    const int node = blockIdx.x * 4 + (threadIdx.x >> 6);
    const float a = A[(size_t)node * 64 + lane];
    float p0 = a * W8[lane * 2 + 0];
    float p1 = a * W8[lane * 2 + 1];
    for (int o = 32; o > 0; o >>= 1) {
        p0 += __shfl_xor(p0, o);
        p1 += __shfl_xor(p1, o);
    }
    if (lane == 0) {
        T8[node * 2 + 0] = p0;
        T8[node * 2 + 1] = p1;
    }
}

// wave per node; lane = (edge j 0..31) x (col c 0..1). fp32.
__global__ void __launch_bounds__(256) gather2(const float* __restrict__ T8,
                                               const float* __restrict__ b8,
                                               const float* __restrict__ dinv,
                                               const int* __restrict__ row_ptr,
                                               const int2* __restrict__ epack,
                                               float* __restrict__ out) {
    const int lane = threadIdx.x & 63;
    const int c = lane & 1;
    const int j = lane >> 1;  // 0..31
    const int node = blockIdx.x * 4 + (threadIdx.x >> 6);
    const int s = row_ptr[node];
    const int e = row_ptr[node + 1];
    float acc = 0.f;
    for (int i = s + j; i < e; i += 32) {
        int2 p = epack[i];
        acc += __int_as_float(p.y) * T8[(size_t)p.x * 2 + c];
    }
    acc += __shfl_xor(acc, 2);
    acc += __shfl_xor(acc, 4);
    acc += __shfl_xor(acc, 8);
    acc += __shfl_xor(acc, 16);
    acc += __shfl_xor(acc, 32);
    if (j == 0) {
        const float dv = dinv[node];
        out[(size_t)node * 2 + c] = b8[c] + dv * dv * T8[(size_t)node * 2 + c] + acc;
    }
}

// ---------------- launcher ----------------

extern "C" void kernel_launch(void* const* d_in, const int* in_sizes, int n_in,
                              void* d_out, int out_size, void* d_ws, size_t ws_size,
                              hipStream_t stream) {
    const float* x  = (const float*)d_in[0];
    const int*   ei = (const int*)d_in[1];   // [2, NE]: [0:NE)=row(src), [NE:2NE)=col(dst)
    const float* ea = (const float*)d_in[2];
    const float* W1 = (const float*)d_in[3];
    const float* b1 = (const float*)d_in[4];
    const float* W2 = (const float*)d_in[5];
    const float* b2 = (const float*)d_in[6];
    const float* W3 = (const float*)d_in[7];
    const float* b3 = (const float*)d_in[8];
    const float* W4 = (const float*)d_in[9];
    const float* b4 = (const float*)d_in[10];
    const float* W5 = (const float*)d_in[11];
    const float* b5 = (const float*)d_in[12];
    const float* W8 = (const float*)d_in[13];
    const float* b8 = (const float*)d_in[14];
    float* out = (float*)d_out;

    // workspace layout (fp32/i32 words)
    unsigned short* Tb = (unsigned short*)d_ws;            // NN*64 bf16 (= NN*32 words)
    float* A      = (float*)d_ws + (size_t)NN * 32;        // NN*64 fp32
    int*   rank   = (int*)A;                               // aliases A (dead before gather1)
    int2*  epack  = (int2*)(A + (size_t)NN * 64);          // NE int2
    unsigned long long* cntdeg = (unsigned long long*)(epack + NE);  // NN ull
    float* dinv   = (float*)(cntdeg + NN);                 // NN
    int*   row_ptr= (int*)(dinv + NN);                     // NN+1
    float* T8     = (float*)(row_ptr + NN + 1);            // NN*2
    int*   blocksum  = (int*)(T8 + (size_t)NN * 2);        // 256
    int*   blockbase = blocksum + 256;                     // 256

    const int* e_row = ei;
    const int* e_col = ei + NE;

    (void)hipMemsetAsync(cntdeg, 0, (size_t)NN * 8, stream);

    // deg_count (4096 blocks) + layer-1 mm (1024 blocks), interleaved 4:1
    setup_mm<<<5120, 256, 0, stream>>>(e_col, ea, cntdeg, rank, x, W1, Tb);
    scan1<<<NN / 256, 256, 0, stream>>>(cntdeg, row_ptr, blocksum, dinv);
    scan2<<<1, 256, 0, stream>>>(blocksum, blockbase, row_ptr);
    scan3<<<NN / 256, 256, 0, stream>>>(row_ptr, blockbase);
    fill_kernel<<<NE / 256, 256, 0, stream>>>(e_row, e_col, ea, dinv, row_ptr, rank, epack);

    // layer 1 aggregate (Tb already = x@W1 in bf16)
    gather64b<true><<<NN / 16, 256, 0, stream>>>(Tb, b1, dinv, row_ptr, epack, A);
    // layers 2..5
    mm64k<<<NN / 64, 256, 0, stream>>>(A, W2, Tb);
    gather64b<true><<<NN / 16, 256, 0, stream>>>(Tb, b2, dinv, row_ptr, epack, A);
    mm64k<<<NN / 64, 256, 0, stream>>>(A, W3, Tb);
    gather64b<true><<<NN / 16, 256, 0, stream>>>(Tb, b3, dinv, row_ptr, epack, A);
    mm64k<<<NN / 64, 256, 0, stream>>>(A, W4, Tb);
    gather64b<true><<<NN / 16, 256, 0, stream>>>(Tb, b4, dinv, row_ptr, epack, A);
    mm64k<<<NN / 64, 256, 0, stream>>>(A, W5, Tb);
    gather64b<true><<<NN / 16, 256, 0, stream>>>(Tb, b5, dinv, row_ptr, epack, A);
    // layer 8: transform first (64 -> 2) in fp32, then aggregate in 2-dim space
    mm2<<<NN / 4, 256, 0, stream>>>(A, W8, T8);
    gather2<<<NN / 4, 256, 0, stream>>>(T8, b8, dinv, row_ptr, epack, out);
}

// Round 10
// 281.678 us; speedup vs baseline: 1.9218x; 1.1226x over previous
//
#include <hip/hip_runtime.h>
#include <hip/hip_bf16.h>
#include <math.h>

#define NN 65536
#define NE 1048576
#define DEG_SCALE 33554432.0f  // 2^25

__device__ inline float4 f4fma(float s, float4 v, float4 a) {
    a.x = fmaf(s, v.x, a.x);
    a.y = fmaf(s, v.y, a.y);
    a.z = fmaf(s, v.z, a.z);
    a.w = fmaf(s, v.w, a.w);
    return a;
}

__device__ inline unsigned pack2bf(float a, float b) {
    __hip_bfloat16 ha = __float2bfloat16(a), hb = __float2bfloat16(b);
    return (unsigned)*reinterpret_cast<unsigned short*>(&ha) |
           ((unsigned)*reinterpret_cast<unsigned short*>(&hb) << 16);
}

__device__ inline void bfx8(uint4 v, float* f) {  // 8 bf16 -> 8 fp32
    f[0] = __uint_as_float(v.x << 16);
    f[1] = __uint_as_float(v.x & 0xffff0000u);
    f[2] = __uint_as_float(v.y << 16);
    f[3] = __uint_as_float(v.y & 0xffff0000u);
    f[4] = __uint_as_float(v.z << 16);
    f[5] = __uint_as_float(v.z & 0xffff0000u);
    f[6] = __uint_as_float(v.w << 16);
    f[7] = __uint_as_float(v.w & 0xffff0000u);
}

// mm body, fp32 A input: C[64x64](bf16) = A[64 x K](fp32) @ W[K x 64](fp32)
template <int K>
__device__ void mm64_body_bf(const float* __restrict__ A, const float* __restrict__ W,
                             unsigned short* __restrict__ Cb, int node0, int tid) {
    __shared__ float As[64 * 68];
    __shared__ float Ws[64 * 64];
    const int tx = tid & 15;
    const int ty = tid >> 4;
    float4 acc[4];
#pragma unroll
    for (int m = 0; m < 4; ++m) acc[m] = make_float4(0.f, 0.f, 0.f, 0.f);

    for (int kc = 0; kc < K; kc += 64) {
#pragma unroll
        for (int p = 0; p < 4; ++p) {
            int idx = tid + p * 256;
            int r = idx >> 4, c4 = idx & 15;
            float4 v = *reinterpret_cast<const float4*>(A + (size_t)(node0 + r) * K + kc + c4 * 4);
            *reinterpret_cast<float4*>(&As[r * 68 + c4 * 4]) = v;
        }
#pragma unroll
        for (int p = 0; p < 4; ++p) {
            int idx = tid + p * 256;
            int r = idx >> 4, c4 = idx & 15;
            float4 v = *reinterpret_cast<const float4*>(W + (size_t)(kc + r) * 64 + c4 * 4);
            *reinterpret_cast<float4*>(&Ws[r * 64 + c4 * 4]) = v;
        }
        __syncthreads();
#pragma unroll 16
        for (int k = 0; k < 64; ++k) {
            float4 w = *reinterpret_cast<const float4*>(&Ws[k * 64 + tx * 4]);
            float a0 = As[(ty * 4 + 0) * 68 + k];
            float a1 = As[(ty * 4 + 1) * 68 + k];
            float a2 = As[(ty * 4 + 2) * 68 + k];
            float a3 = As[(ty * 4 + 3) * 68 + k];
            acc[0] = f4fma(a0, w, acc[0]);
            acc[1] = f4fma(a1, w, acc[1]);
            acc[2] = f4fma(a2, w, acc[2]);
            acc[3] = f4fma(a3, w, acc[3]);
        }
        __syncthreads();
    }
#pragma unroll
    for (int m = 0; m < 4; ++m) {
        uint2 pk;
        pk.x = pack2bf(acc[m].x, acc[m].y);
        pk.y = pack2bf(acc[m].z, acc[m].w);
        *reinterpret_cast<uint2*>(Cb + (size_t)(node0 + ty * 4 + m) * 64 + tx * 4) = pk;
    }
}

// mm body, bf16 A input: C[64x64](bf16) = A[64 x 64](bf16) @ W[64 x 64](fp32)
__device__ void mm64_body_bb(const unsigned short* __restrict__ Ab, const float* __restrict__ W,
                             unsigned short* __restrict__ Cb, int node0, int tid) {
    __shared__ float As[64 * 68];
    __shared__ float Ws[64 * 64];
    const int tx = tid & 15;
    const int ty = tid >> 4;
    const uint4* A4 = reinterpret_cast<const uint4*>(Ab);
#pragma unroll
    for (int pp = 0; pp < 2; ++pp) {
        int idx = tid + pp * 256;       // 0..511 -> 64 rows x 8 uint4
        int r = idx >> 3, c8 = idx & 7;
        float f[8];
        bfx8(A4[(size_t)(node0 + r) * 8 + c8], f);
#pragma unroll
        for (int k = 0; k < 8; ++k) As[r * 68 + c8 * 8 + k] = f[k];
    }
#pragma unroll
    for (int p = 0; p < 4; ++p) {
        int idx = tid + p * 256;
        int r = idx >> 4, c4 = idx & 15;
        float4 v = *reinterpret_cast<const float4*>(W + (size_t)r * 64 + c4 * 4);
        *reinterpret_cast<float4*>(&Ws[r * 64 + c4 * 4]) = v;
    }
    __syncthreads();
    float4 acc[4];
#pragma unroll
    for (int m = 0; m < 4; ++m) acc[m] = make_float4(0.f, 0.f, 0.f, 0.f);
#pragma unroll 16
    for (int k = 0; k < 64; ++k) {
        float4 w = *reinterpret_cast<const float4*>(&Ws[k * 64 + tx * 4]);
        float a0 = As[(ty * 4 + 0) * 68 + k];
        float a1 = As[(ty * 4 + 1) * 68 + k];
        float a2 = As[(ty * 4 + 2) * 68 + k];
        float a3 = As[(ty * 4 + 3) * 68 + k];
        acc[0] = f4fma(a0, w, acc[0]);
        acc[1] = f4fma(a1, w, acc[1]);
        acc[2] = f4fma(a2, w, acc[2]);
        acc[3] = f4fma(a3, w, acc[3]);
    }
#pragma unroll
    for (int m = 0; m < 4; ++m) {
        uint2 pk;
        pk.x = pack2bf(acc[m].x, acc[m].y);
        pk.y = pack2bf(acc[m].z, acc[m].w);
        *reinterpret_cast<uint2*>(Cb + (size_t)(node0 + ty * 4 + m) * 64 + tx * 4) = pk;
    }
}

// ---------------- setup (merged with layer-1 mm) ----------------

__global__ void __launch_bounds__(256) setup_mm(const int* __restrict__ col,
                                                const float* __restrict__ ew,
                                                unsigned long long* __restrict__ cntdeg,
                                                int* __restrict__ rank,
                                                const float* __restrict__ x,
                                                const float* __restrict__ W1,
                                                unsigned short* __restrict__ Tb) {
    const int bid = blockIdx.x;
    const int tid = threadIdx.x;
    if (bid % 5 == 0) {
        mm64_body_bf<128>(x, W1, Tb, (bid / 5) * 64, tid);
    } else {
        int e = (bid - bid / 5 - 1) * 256 + tid;
        if (e < NE) {
            int c = col[e];
            unsigned long long p =
                (1ull << 32) | (unsigned long long)__float2uint_rn(ew[e] * DEG_SCALE);
            unsigned long long old = atomicAdd(&cntdeg[c], p);
            rank[e] = (int)(old >> 32);
        }
    }
}

// phase 1: per-block (256 nodes) exclusive scan of counts; emit block total + dinv.
__global__ void __launch_bounds__(256) scan1(const unsigned long long* __restrict__ cntdeg,
                                             int* __restrict__ row_ptr,
                                             int* __restrict__ blocksum,
                                             float* __restrict__ dinv) {
    __shared__ int ls[256];
    const int t = threadIdx.x;
    const int i = blockIdx.x * 256 + t;
    unsigned long long v = cntdeg[i];
    const int c = (int)(v >> 32);
    float deg = (float)(unsigned)(v & 0xffffffffull) * (1.0f / DEG_SCALE) + 1.0f;
    dinv[i] = 1.0f / sqrtf(deg);
    ls[t] = c;
    __syncthreads();
#pragma unroll
    for (int off = 1; off < 256; off <<= 1) {
        int u = (t >= off) ? ls[t - off] : 0;
        __syncthreads();
        ls[t] += u;
        __syncthreads();
    }
    row_ptr[i] = ls[t] - c;  // exclusive
    if (t == 255) blocksum[blockIdx.x] = ls[255];
}

__global__ void __launch_bounds__(256) scan2(int* __restrict__ blocksum,
                                             int* __restrict__ blockbase,
                                             int* __restrict__ row_ptr) {
    __shared__ int ls[256];
    const int t = threadIdx.x;
    const int c = blocksum[t];
    ls[t] = c;
    __syncthreads();
#pragma unroll
    for (int off = 1; off < 256; off <<= 1) {
        int u = (t >= off) ? ls[t - off] : 0;
        __syncthreads();
        ls[t] += u;
        __syncthreads();
    }
    blockbase[t] = ls[t] - c;
    if (t == 255) row_ptr[NN] = ls[255];
}

__global__ void __launch_bounds__(256) scan3(int* __restrict__ row_ptr,
                                             const int* __restrict__ blockbase) {
    const int i = blockIdx.x * 256 + threadIdx.x;
    row_ptr[i] += blockbase[blockIdx.x];
}

// atomic-free CSR fill using precomputed rank.
__global__ void __launch_bounds__(256) fill_kernel(const int* __restrict__ row,
                                                   const int* __restrict__ col,
                                                   const float* __restrict__ ew,
                                                   const float* __restrict__ dinv,
                                                   const int* __restrict__ row_ptr,
                                                   const int* __restrict__ rank,
                                                   int2* __restrict__ epack) {
    int e = blockIdx.x * 256 + threadIdx.x;
    if (e < NE) {
        int c = col[e], r = row[e];
        int idx = row_ptr[c] + rank[e];
        int2 p;
        p.x = r;
        p.y = __float_as_int(dinv[r] * ew[e] * dinv[c]);
        epack[idx] = p;
    }
}

// ---------------- per-layer kernels ----------------

__global__ void __launch_bounds__(256) mm64k(const unsigned short* __restrict__ Ab,
                                             const float* __restrict__ W,
                                             unsigned short* __restrict__ Tb) {
    mm64_body_bb(Ab, W, Tb, blockIdx.x * 64, threadIdx.x);
}

// out[n][:] = act( b + dinv[n]^2*T[n] + sum_e enorm[e]*T[esrc[e]] ); T, out in bf16.
// 8 lanes per node (32 nodes/block); uint4 (16B) row loads; 8-wide clamped-predicated loop
// -> 64 row loads in flight per wave.
template <bool RELU>
__global__ void __launch_bounds__(256) gather64c(const unsigned short* __restrict__ Tb,
                                                 const float* __restrict__ bias,
                                                 const float* __restrict__ dinv,
                                                 const int* __restrict__ row_ptr,
                                                 const int2* __restrict__ epack,
                                                 unsigned short* __restrict__ outb) {
    const int tid = threadIdx.x;
    const int l = tid & 7;                        // uint4 index in row (8 bf16 cols)
    const int node = blockIdx.x * 32 + (tid >> 3);
    const uint4* T4 = reinterpret_cast<const uint4*>(Tb);

    const float dv = dinv[node];
    float acc[8];
    {
        float ts[8];
        bfx8(T4[(size_t)node * 8 + l], ts);
        float4 bA = *reinterpret_cast<const float4*>(bias + l * 8);
        float4 bB = *reinterpret_cast<const float4*>(bias + l * 8 + 4);
        acc[0] = bA.x + dv * dv * ts[0];
        acc[1] = bA.y + dv * dv * ts[1];
        acc[2] = bA.z + dv * dv * ts[2];
        acc[3] = bA.w + dv * dv * ts[3];
        acc[4] = bB.x + dv * dv * ts[4];
        acc[5] = bB.y + dv * dv * ts[5];
        acc[6] = bB.z + dv * dv * ts[6];
        acc[7] = bB.w + dv * dv * ts[7];
    }

    const int s = row_ptr[node];
    const int e = row_ptr[node + 1];
    for (int i0 = s; i0 < e; i0 += 8) {
        int2 p[8];
#pragma unroll
        for (int j = 0; j < 8; ++j) {
            int ii = i0 + j;
            p[j] = epack[ii < e ? ii : i0];       // slot 0 always valid
        }
        uint4 r[8];
        float n[8];
#pragma unroll
        for (int j = 0; j < 8; ++j) {
            n[j] = (i0 + j < e) ? __int_as_float(p[j].y) : 0.0f;
            r[j] = T4[(size_t)p[j].x * 8 + l];
        }
#pragma unroll
        for (int j = 0; j < 8; ++j) {
            float f[8];
            bfx8(r[j], f);
#pragma unroll
            for (int k = 0; k < 8; ++k) acc[k] = fmaf(n[j], f[k], acc[k]);
        }
    }
    if (RELU) {
#pragma unroll
        for (int k = 0; k < 8; ++k) acc[k] = fmaxf(acc[k], 0.f);
    }
    uint4 o;
    o.x = pack2bf(acc[0], acc[1]);
    o.y = pack2bf(acc[2], acc[3]);
    o.z = pack2bf(acc[4], acc[5]);
    o.w = pack2bf(acc[6], acc[7]);
    reinterpret_cast<uint4*>(outb)[(size_t)node * 8 + l] = o;
}

// T8[NN x 2] = Ab[NN x 64](bf16) @ W8[64 x 2]; wave per node, shuffle reduction.
__global__ void __launch_bounds__(256) mm2(const unsigned short* __restrict__ Ab,
                                           const float* __restrict__ W8,
                                           float* __restrict__ T8) {
    const int lane = threadIdx.x & 63;
    const int node = blockIdx.x * 4 + (threadIdx.x >> 6);
    const float a = __uint_as_float(((unsigned)Ab[(size_t)node * 64 + lane]) << 16);
    float p0 = a * W8[lane * 2 + 0];
    float p1 = a * W8[lane * 2 + 1];
    for (int o = 32; o > 0; o >>= 1) {
        p0 += __shfl_xor(p0, o);
        p1 += __shfl_xor(p1, o);
    }
    if (lane == 0) {
        T8[node * 2 + 0] = p0;
        T8[node * 2 + 1] = p1;
    }
}

// wave per node; lane = (edge j 0..31) x (col c 0..1). fp32.
__global__ void __launch_bounds__(256) gather2(const float* __restrict__ T8,
                                               const float* __restrict__ b8,
                                               const float* __restrict__ dinv,
                                               const int* __restrict__ row_ptr,
                                               const int2* __restrict__ epack,
                                               float* __restrict__ out) {
    const int lane = threadIdx.x & 63;
    const int c = lane & 1;
    const int j = lane >> 1;  // 0..31
    const int node = blockIdx.x * 4 + (threadIdx.x >> 6);
    const int s = row_ptr[node];
    const int e = row_ptr[node + 1];
    float acc = 0.f;
    for (int i = s + j; i < e; i += 32) {
        int2 p = epack[i];
        acc += __int_as_float(p.y) * T8[(size_t)p.x * 2 + c];
    }
    acc += __shfl_xor(acc, 2);
    acc += __shfl_xor(acc, 4);
    acc += __shfl_xor(acc, 8);
    acc += __shfl_xor(acc, 16);
    acc += __shfl_xor(acc, 32);
    if (j == 0) {
        const float dv = dinv[node];
        out[(size_t)node * 2 + c] = b8[c] + dv * dv * T8[(size_t)node * 2 + c] + acc;
    }
}

// ---------------- launcher ----------------

extern "C" void kernel_launch(void* const* d_in, const int* in_sizes, int n_in,
                              void* d_out, int out_size, void* d_ws, size_t ws_size,
                              hipStream_t stream) {
    const float* x  = (const float*)d_in[0];
    const int*   ei = (const int*)d_in[1];   // [2, NE]: [0:NE)=row(src), [NE:2NE)=col(dst)
    const float* ea = (const float*)d_in[2];
    const float* W1 = (const float*)d_in[3];
    const float* b1 = (const float*)d_in[4];
    const float* W2 = (const float*)d_in[5];
    const float* b2 = (const float*)d_in[6];
    const float* W3 = (const float*)d_in[7];
    const float* b3 = (const float*)d_in[8];
    const float* W4 = (const float*)d_in[9];
    const float* b4 = (const float*)d_in[10];
    const float* W5 = (const float*)d_in[11];
    const float* b5 = (const float*)d_in[12];
    const float* W8 = (const float*)d_in[13];
    const float* b8 = (const float*)d_in[14];
    float* out = (float*)d_out;

    // workspace layout
    unsigned short* Tb = (unsigned short*)d_ws;            // NN*64 bf16 (8 MB)
    unsigned short* Ab = Tb + (size_t)NN * 64;             // NN*64 bf16 (8 MB)
    int*   rank   = (int*)Ab;                              // aliases Ab (dead before layer-1 gather)
    int2*  epack  = (int2*)(Ab + (size_t)NN * 64);         // NE int2 (8 MB)
    unsigned long long* cntdeg = (unsigned long long*)(epack + NE);  // NN ull
    float* dinv   = (float*)(cntdeg + NN);                 // NN
    int*   row_ptr= (int*)(dinv + NN);                     // NN+1
    float* T8     = (float*)(row_ptr + NN + 1);            // NN*2
    int*   blocksum  = (int*)(T8 + (size_t)NN * 2);        // 256
    int*   blockbase = blocksum + 256;                     // 256

    const int* e_row = ei;
    const int* e_col = ei + NE;

    (void)hipMemsetAsync(cntdeg, 0, (size_t)NN * 8, stream);

    // deg_count (4096 blocks) + layer-1 mm (1024 blocks), interleaved 4:1
    setup_mm<<<5120, 256, 0, stream>>>(e_col, ea, cntdeg, rank, x, W1, Tb);
    scan1<<<NN / 256, 256, 0, stream>>>(cntdeg, row_ptr, blocksum, dinv);
    scan2<<<1, 256, 0, stream>>>(blocksum, blockbase, row_ptr);
    scan3<<<NN / 256, 256, 0, stream>>>(row_ptr, blockbase);
    fill_kernel<<<NE / 256, 256, 0, stream>>>(e_row, e_col, ea, dinv, row_ptr, rank, epack);

    // layer 1 aggregate (Tb already = x@W1 in bf16) -> Ab
    gather64c<true><<<NN / 32, 256, 0, stream>>>(Tb, b1, dinv, row_ptr, epack, Ab);
    // layers 2..5 (all-bf16 activations)
    mm64k<<<NN / 64, 256, 0, stream>>>(Ab, W2, Tb);
    gather64c<true><<<NN / 32, 256, 0, stream>>>(Tb, b2, dinv, row_ptr, epack, Ab);
    mm64k<<<NN / 64, 256, 0, stream>>>(Ab, W3, Tb);
    gather64c<true><<<NN / 32, 256, 0, stream>>>(Tb, b3, dinv, row_ptr, epack, Ab);
    mm64k<<<NN / 64, 256, 0, stream>>>(Ab, W4, Tb);
    gather64c<true><<<NN / 32, 256, 0, stream>>>(Tb, b4, dinv, row_ptr, epack, Ab);
    mm64k<<<NN / 64, 256, 0, stream>>>(Ab, W5, Tb);
    gather64c<true><<<NN / 32, 256, 0, stream>>>(Tb, b5, dinv, row_ptr, epack, Ab);
    // layer 8: transform first (64 -> 2) in fp32, then aggregate in 2-dim space
    mm2<<<NN / 4, 256, 0, stream>>>(Ab, W8, T8);
    gather2<<<NN / 4, 256, 0, stream>>>(T8, b8, dinv, row_ptr, epack, out);
}

// Round 11
// 225.714 us; speedup vs baseline: 2.3983x; 1.2479x over previous
//
#include <hip/hip_runtime.h>
#include <hip/hip_bf16.h>
#include <math.h>

#define NN 65536
#define NE 1048576
#define DEG_SCALE 33554432.0f  // 2^25

__device__ inline float4 f4fma(float s, float4 v, float4 a) {
    a.x = fmaf(s, v.x, a.x);
    a.y = fmaf(s, v.y, a.y);
    a.z = fmaf(s, v.z, a.z);
    a.w = fmaf(s, v.w, a.w);
    return a;
}

__device__ inline unsigned pack2bf(float a, float b) {
    __hip_bfloat16 ha = __float2bfloat16(a), hb = __float2bfloat16(b);
    return (unsigned)*reinterpret_cast<unsigned short*>(&ha) |
           ((unsigned)*reinterpret_cast<unsigned short*>(&hb) << 16);
}

__device__ inline void bfx8(uint4 v, float* f) {  // 8 bf16 -> 8 fp32
    f[0] = __uint_as_float(v.x << 16);
    f[1] = __uint_as_float(v.x & 0xffff0000u);
    f[2] = __uint_as_float(v.y << 16);
    f[3] = __uint_as_float(v.y & 0xffff0000u);
    f[4] = __uint_as_float(v.z << 16);
    f[5] = __uint_as_float(v.z & 0xffff0000u);
    f[6] = __uint_as_float(v.w << 16);
    f[7] = __uint_as_float(v.w & 0xffff0000u);
}

// mm body, fp32 A input: C[64x64](bf16) = A[64 x K](fp32) @ W[K x 64](fp32)
template <int K>
__device__ void mm64_body_bf(const float* __restrict__ A, const float* __restrict__ W,
                             unsigned short* __restrict__ Cb, int node0, int tid) {
    __shared__ float As[64 * 68];
    __shared__ float Ws[64 * 64];
    const int tx = tid & 15;
    const int ty = tid >> 4;
    float4 acc[4];
#pragma unroll
    for (int m = 0; m < 4; ++m) acc[m] = make_float4(0.f, 0.f, 0.f, 0.f);

    for (int kc = 0; kc < K; kc += 64) {
#pragma unroll
        for (int p = 0; p < 4; ++p) {
            int idx = tid + p * 256;
            int r = idx >> 4, c4 = idx & 15;
            float4 v = *reinterpret_cast<const float4*>(A + (size_t)(node0 + r) * K + kc + c4 * 4);
            *reinterpret_cast<float4*>(&As[r * 68 + c4 * 4]) = v;
        }
#pragma unroll
        for (int p = 0; p < 4; ++p) {
            int idx = tid + p * 256;
            int r = idx >> 4, c4 = idx & 15;
            float4 v = *reinterpret_cast<const float4*>(W + (size_t)(kc + r) * 64 + c4 * 4);
            *reinterpret_cast<float4*>(&Ws[r * 64 + c4 * 4]) = v;
        }
        __syncthreads();
#pragma unroll 16
        for (int k = 0; k < 64; ++k) {
            float4 w = *reinterpret_cast<const float4*>(&Ws[k * 64 + tx * 4]);
            float a0 = As[(ty * 4 + 0) * 68 + k];
            float a1 = As[(ty * 4 + 1) * 68 + k];
            float a2 = As[(ty * 4 + 2) * 68 + k];
            float a3 = As[(ty * 4 + 3) * 68 + k];
            acc[0] = f4fma(a0, w, acc[0]);
            acc[1] = f4fma(a1, w, acc[1]);
            acc[2] = f4fma(a2, w, acc[2]);
            acc[3] = f4fma(a3, w, acc[3]);
        }
        __syncthreads();
    }
#pragma unroll
    for (int m = 0; m < 4; ++m) {
        uint2 pk;
        pk.x = pack2bf(acc[m].x, acc[m].y);
        pk.y = pack2bf(acc[m].z, acc[m].w);
        *reinterpret_cast<uint2*>(Cb + (size_t)(node0 + ty * 4 + m) * 64 + tx * 4) = pk;
    }
}

// ---------------- setup (merged with layer-1 mm) ----------------

__global__ void __launch_bounds__(256) setup_mm(const int* __restrict__ col,
                                                const float* __restrict__ ew,
                                                unsigned long long* __restrict__ cntdeg,
                                                int* __restrict__ rank,
                                                const float* __restrict__ x,
                                                const float* __restrict__ W1,
                                                unsigned short* __restrict__ Tb) {
    const int bid = blockIdx.x;
    const int tid = threadIdx.x;
    if (bid % 5 == 0) {
        mm64_body_bf<128>(x, W1, Tb, (bid / 5) * 64, tid);
    } else {
        int e = (bid - bid / 5 - 1) * 256 + tid;
        if (e < NE) {
            int c = col[e];
            unsigned long long p =
                (1ull << 32) | (unsigned long long)__float2uint_rn(ew[e] * DEG_SCALE);
            unsigned long long old = atomicAdd(&cntdeg[c], p);
            rank[e] = (int)(old >> 32);
        }
    }
}

// phase 1: per-block (256 nodes) exclusive scan of counts; emit block total + dinv.
__global__ void __launch_bounds__(256) scan1(const unsigned long long* __restrict__ cntdeg,
                                             int* __restrict__ row_ptr,
                                             int* __restrict__ blocksum,
                                             float* __restrict__ dinv) {
    __shared__ int ls[256];
    const int t = threadIdx.x;
    const int i = blockIdx.x * 256 + t;
    unsigned long long v = cntdeg[i];
    const int c = (int)(v >> 32);
    float deg = (float)(unsigned)(v & 0xffffffffull) * (1.0f / DEG_SCALE) + 1.0f;
    dinv[i] = 1.0f / sqrtf(deg);
    ls[t] = c;
    __syncthreads();
#pragma unroll
    for (int off = 1; off < 256; off <<= 1) {
        int u = (t >= off) ? ls[t - off] : 0;
        __syncthreads();
        ls[t] += u;
        __syncthreads();
    }
    row_ptr[i] = ls[t] - c;  // exclusive
    if (t == 255) blocksum[blockIdx.x] = ls[255];
}

__global__ void __launch_bounds__(256) scan2(int* __restrict__ blocksum,
                                             int* __restrict__ blockbase,
                                             int* __restrict__ row_ptr) {
    __shared__ int ls[256];
    const int t = threadIdx.x;
    const int c = blocksum[t];
    ls[t] = c;
    __syncthreads();
#pragma unroll
    for (int off = 1; off < 256; off <<= 1) {
        int u = (t >= off) ? ls[t - off] : 0;
        __syncthreads();
        ls[t] += u;
        __syncthreads();
    }
    blockbase[t] = ls[t] - c;
    if (t == 255) row_ptr[NN] = ls[255];
}

__global__ void __launch_bounds__(256) scan3(int* __restrict__ row_ptr,
                                             const int* __restrict__ blockbase) {
    const int i = blockIdx.x * 256 + threadIdx.x;
    row_ptr[i] += blockbase[blockIdx.x];
}

// atomic-free CSR fill using precomputed rank.
__global__ void __launch_bounds__(256) fill_kernel(const int* __restrict__ row,
                                                   const int* __restrict__ col,
                                                   const float* __restrict__ ew,
                                                   const float* __restrict__ dinv,
                                                   const int* __restrict__ row_ptr,
                                                   const int* __restrict__ rank,
                                                   int2* __restrict__ epack) {
    int e = blockIdx.x * 256 + threadIdx.x;
    if (e < NE) {
        int c = col[e], r = row[e];
        int idx = row_ptr[c] + rank[e];
        int2 p;
        p.x = r;
        p.y = __float_as_int(dinv[r] * ew[e] * dinv[c]);
        epack[idx] = p;
    }
}

// ---------------- fused layer kernels ----------------

// gather phase shared by gmm64/gmm2: 8 lanes per node, 8-wide clamped-predicated loop.
// acc[8] = relu( b + dinv^2*T[node] + sum_e enorm*T[src] ), all fp32.
__device__ inline void gather_node(const uint4* __restrict__ T4,
                                   const float* __restrict__ bias,
                                   const float* __restrict__ dinv,
                                   const int* __restrict__ row_ptr,
                                   const int2* __restrict__ epack,
                                   int node, int l, float* acc) {
    const float dv = dinv[node];
    {
        float ts[8];
        bfx8(T4[(size_t)node * 8 + l], ts);
        float4 bA = *reinterpret_cast<const float4*>(bias + l * 8);
        float4 bB = *reinterpret_cast<const float4*>(bias + l * 8 + 4);
        acc[0] = bA.x + dv * dv * ts[0];
        acc[1] = bA.y + dv * dv * ts[1];
        acc[2] = bA.z + dv * dv * ts[2];
        acc[3] = bA.w + dv * dv * ts[3];
        acc[4] = bB.x + dv * dv * ts[4];
        acc[5] = bB.y + dv * dv * ts[5];
        acc[6] = bB.z + dv * dv * ts[6];
        acc[7] = bB.w + dv * dv * ts[7];
    }
    const int s = row_ptr[node];
    const int e = row_ptr[node + 1];
    for (int i0 = s; i0 < e; i0 += 8) {
        int2 p[8];
#pragma unroll
        for (int j = 0; j < 8; ++j) {
            int ii = i0 + j;
            p[j] = epack[ii < e ? ii : i0];       // slot 0 always valid
        }
        uint4 r[8];
        float n[8];
#pragma unroll
        for (int j = 0; j < 8; ++j) {
            n[j] = (i0 + j < e) ? __int_as_float(p[j].y) : 0.0f;
            r[j] = T4[(size_t)p[j].x * 8 + l];
        }
#pragma unroll
        for (int j = 0; j < 8; ++j) {
            float f[8];
            bfx8(r[j], f);
#pragma unroll
            for (int k = 0; k < 8; ++k) acc[k] = fmaf(n[j], f[k], acc[k]);
        }
    }
#pragma unroll
    for (int k = 0; k < 8; ++k) acc[k] = fmaxf(acc[k], 0.f);
}

// fused: A = relu(agg(Tb)+b) (32 nodes -> LDS), then Tbn = A @ W (64x64).
__global__ void __launch_bounds__(256) gmm64(const unsigned short* __restrict__ Tb,
                                             const float* __restrict__ bias,
                                             const float* __restrict__ dinv,
                                             const int* __restrict__ row_ptr,
                                             const int2* __restrict__ epack,
                                             const float* __restrict__ W,
                                             unsigned short* __restrict__ Tbn) {
    __shared__ float As[32 * 68];
    __shared__ float Ws[64 * 64];
    const int tid = threadIdx.x;
    const int node0 = blockIdx.x * 32;

    // stage W (16 KB)
#pragma unroll
    for (int p = 0; p < 4; ++p) {
        int idx = tid + p * 256;
        int r = idx >> 4, c4 = idx & 15;
        *reinterpret_cast<float4*>(&Ws[r * 64 + c4 * 4]) =
            *reinterpret_cast<const float4*>(W + (size_t)r * 64 + c4 * 4);
    }

    // gather 32 nodes -> As
    const int l = tid & 7;
    const int slot = tid >> 3;
    float acc[8];
    gather_node(reinterpret_cast<const uint4*>(Tb), bias, dinv, row_ptr, epack,
                node0 + slot, l, acc);
    *reinterpret_cast<float4*>(&As[slot * 68 + l * 8]) =
        make_float4(acc[0], acc[1], acc[2], acc[3]);
    *reinterpret_cast<float4*>(&As[slot * 68 + l * 8 + 4]) =
        make_float4(acc[4], acc[5], acc[6], acc[7]);
    __syncthreads();

    // mm: 2 rows x 4 cols per thread
    const int tx = tid & 15;
    const int ty = tid >> 4;
    float4 c0 = make_float4(0.f, 0.f, 0.f, 0.f);
    float4 c1 = make_float4(0.f, 0.f, 0.f, 0.f);
#pragma unroll 16
    for (int k = 0; k < 64; ++k) {
        float4 w = *reinterpret_cast<const float4*>(&Ws[k * 64 + tx * 4]);
        float a0 = As[(ty * 2 + 0) * 68 + k];
        float a1 = As[(ty * 2 + 1) * 68 + k];
        c0 = f4fma(a0, w, c0);
        c1 = f4fma(a1, w, c1);
    }
    uint2 pk;
    pk.x = pack2bf(c0.x, c0.y);
    pk.y = pack2bf(c0.z, c0.w);
    *reinterpret_cast<uint2*>(Tbn + (size_t)(node0 + ty * 2 + 0) * 64 + tx * 4) = pk;
    pk.x = pack2bf(c1.x, c1.y);
    pk.y = pack2bf(c1.z, c1.w);
    *reinterpret_cast<uint2*>(Tbn + (size_t)(node0 + ty * 2 + 1) * 64 + tx * 4) = pk;
}

// fused final: A = relu(agg(Tb)+b) (32 nodes -> LDS), then T8 = A @ W8 (64x2), fp32.
__global__ void __launch_bounds__(256) gmm2(const unsigned short* __restrict__ Tb,
                                            const float* __restrict__ bias,
                                            const float* __restrict__ dinv,
                                            const int* __restrict__ row_ptr,
                                            const int2* __restrict__ epack,
                                            const float* __restrict__ W8,
                                            float* __restrict__ T8) {
    __shared__ float As[32 * 68];
    const int tid = threadIdx.x;
    const int node0 = blockIdx.x * 32;
    const int l = tid & 7;
    const int slot = tid >> 3;
    float acc[8];
    gather_node(reinterpret_cast<const uint4*>(Tb), bias, dinv, row_ptr, epack,
                node0 + slot, l, acc);
    *reinterpret_cast<float4*>(&As[slot * 68 + l * 8]) =
        make_float4(acc[0], acc[1], acc[2], acc[3]);
    *reinterpret_cast<float4*>(&As[slot * 68 + l * 8 + 4]) =
        make_float4(acc[4], acc[5], acc[6], acc[7]);
    __syncthreads();
    if (tid < 64) {
        const int nd = tid >> 1, c = tid & 1;
        float s = 0.f;
#pragma unroll 16
        for (int k = 0; k < 64; ++k) s = fmaf(As[nd * 68 + k], W8[k * 2 + c], s);
        T8[(size_t)(node0 + nd) * 2 + c] = s;
    }
}

// wave per node; lane = (edge j 0..31) x (col c 0..1). fp32.
__global__ void __launch_bounds__(256) gather2(const float* __restrict__ T8,
                                               const float* __restrict__ b8,
                                               const float* __restrict__ dinv,
                                               const int* __restrict__ row_ptr,
                                               const int2* __restrict__ epack,
                                               float* __restrict__ out) {
    const int lane = threadIdx.x & 63;
    const int c = lane & 1;
    const int j = lane >> 1;  // 0..31
    const int node = blockIdx.x * 4 + (threadIdx.x >> 6);
    const int s = row_ptr[node];
    const int e = row_ptr[node + 1];
    float acc = 0.f;
    for (int i = s + j; i < e; i += 32) {
        int2 p = epack[i];
        acc += __int_as_float(p.y) * T8[(size_t)p.x * 2 + c];
    }
    acc += __shfl_xor(acc, 2);
    acc += __shfl_xor(acc, 4);
    acc += __shfl_xor(acc, 8);
    acc += __shfl_xor(acc, 16);
    acc += __shfl_xor(acc, 32);
    if (j == 0) {
        const float dv = dinv[node];
        out[(size_t)node * 2 + c] = b8[c] + dv * dv * T8[(size_t)node * 2 + c] + acc;
    }
}

// ---------------- launcher ----------------

extern "C" void kernel_launch(void* const* d_in, const int* in_sizes, int n_in,
                              void* d_out, int out_size, void* d_ws, size_t ws_size,
                              hipStream_t stream) {
    const float* x  = (const float*)d_in[0];
    const int*   ei = (const int*)d_in[1];   // [2, NE]: [0:NE)=row(src), [NE:2NE)=col(dst)
    const float* ea = (const float*)d_in[2];
    const float* W1 = (const float*)d_in[3];
    const float* b1 = (const float*)d_in[4];
    const float* W2 = (const float*)d_in[5];
    const float* b2 = (const float*)d_in[6];
    const float* W3 = (const float*)d_in[7];
    const float* b3 = (const float*)d_in[8];
    const float* W4 = (const float*)d_in[9];
    const float* b4 = (const float*)d_in[10];
    const float* W5 = (const float*)d_in[11];
    const float* b5 = (const float*)d_in[12];
    const float* W8 = (const float*)d_in[13];
    const float* b8 = (const float*)d_in[14];
    float* out = (float*)d_out;

    // workspace layout (~26 MB)
    unsigned short* Tb1 = (unsigned short*)d_ws;           // NN*64 bf16 (8 MB)
    unsigned short* Tb2 = Tb1 + (size_t)NN * 64;           // NN*64 bf16 (8 MB)
    int*   rank   = (int*)Tb2;                             // aliases Tb2 (rank dead before
                                                           //  gmm64 #1 writes Tb2)
    int2*  epack  = (int2*)(Tb2 + (size_t)NN * 64);        // NE int2 (8 MB)
    unsigned long long* cntdeg = (unsigned long long*)(epack + NE);  // NN ull
    float* dinv   = (float*)(cntdeg + NN);                 // NN
    int*   row_ptr= (int*)(dinv + NN);                     // NN+1
    float* T8     = (float*)(row_ptr + NN + 1);            // NN*2
    int*   blocksum  = (int*)(T8 + (size_t)NN * 2);        // 256
    int*   blockbase = blocksum + 256;                     // 256

    const int* e_row = ei;
    const int* e_col = ei + NE;

    (void)hipMemsetAsync(cntdeg, 0, (size_t)NN * 8, stream);

    // deg_count (4096 blocks) + layer-1 mm (1024 blocks), interleaved 4:1
    setup_mm<<<5120, 256, 0, stream>>>(e_col, ea, cntdeg, rank, x, W1, Tb1);
    scan1<<<NN / 256, 256, 0, stream>>>(cntdeg, row_ptr, blocksum, dinv);
    scan2<<<1, 256, 0, stream>>>(blocksum, blockbase, row_ptr);
    scan3<<<NN / 256, 256, 0, stream>>>(row_ptr, blockbase);
    fill_kernel<<<NE / 256, 256, 0, stream>>>(e_row, e_col, ea, dinv, row_ptr, rank, epack);

    // fused layers: gather(Tb,b)+relu -> LDS -> @W -> Tbn
    gmm64<<<NN / 32, 256, 0, stream>>>(Tb1, b1, dinv, row_ptr, epack, W2, Tb2);
    gmm64<<<NN / 32, 256, 0, stream>>>(Tb2, b2, dinv, row_ptr, epack, W3, Tb1);
    gmm64<<<NN / 32, 256, 0, stream>>>(Tb1, b3, dinv, row_ptr, epack, W4, Tb2);
    gmm64<<<NN / 32, 256, 0, stream>>>(Tb2, b4, dinv, row_ptr, epack, W5, Tb1);
    gmm2<<<NN / 32, 256, 0, stream>>>(Tb1, b5, dinv, row_ptr, epack, W8, T8);
    // final aggregate in 2-dim space
    gather2<<<NN / 4, 256, 0, stream>>>(T8, b8, dinv, row_ptr, epack, out);
}